// Round 5
// baseline (461.818 us; speedup 1.0000x reference)
//
#include <hip/hip_runtime.h>

#define D 128

typedef __attribute__((ext_vector_type(4))) float f32x4;
typedef __attribute__((ext_vector_type(8))) short s16x8;

__device__ inline unsigned short f2bf(float x){
  unsigned u = __builtin_bit_cast(unsigned, x);
  u += 0x7FFFu + ((u>>16)&1u);
  return (unsigned short)(u>>16);
}

__device__ inline void gload_lds16(const void* g, void* l){
  __builtin_amdgcn_global_load_lds(
      (const __attribute__((address_space(1))) void*)g,
      (__attribute__((address_space(3))) void*)l, 16, 0, 0);
}

// ---------- CSR build ----------
__global__ void k_hist(const int* __restrict__ dst, int* __restrict__ counts, int E){
  int e = blockIdx.x*256 + threadIdx.x;
  if (e < E) atomicAdd(&counts[dst[e]], 1);
}

__global__ void k_scan1(const int* __restrict__ counts, int* __restrict__ partials, int N){
  __shared__ int sd[256];
  int t = threadIdx.x;
  int base = blockIdx.x*1024 + t*4;
  int s = 0;
  #pragma unroll
  for (int j=0;j<4;j++){ int i=base+j; s += (i<N)?counts[i]:0; }
  sd[t]=s; __syncthreads();
  for (int off=128; off>0; off>>=1){ if (t<off) sd[t]+=sd[t+off]; __syncthreads(); }
  if (t==0) partials[blockIdx.x]=sd[0];
}

__global__ void k_scan2(int* __restrict__ partials, int* __restrict__ row_ptr, int nb, int N){
  __shared__ int sd[1024];
  int t = threadIdx.x;
  if (nb <= 1024){
    int v = (t < nb) ? partials[t] : 0;
    sd[t] = v;
    __syncthreads();
    #pragma unroll
    for (int off=1; off<1024; off<<=1){
      int x = (t >= off) ? sd[t-off] : 0;
      __syncthreads();
      sd[t] += x;
      __syncthreads();
    }
    if (t < nb) partials[t] = sd[t] - v;
    if (t == 1023) row_ptr[N] = sd[1023];
  } else if (t == 0){
    int run=0;
    for (int b=0;b<nb;b++){ int v=partials[b]; partials[b]=run; run+=v; }
    row_ptr[N]=run;
  }
}

__global__ void k_scan3(const int* __restrict__ counts, const int* __restrict__ partials,
                        int* __restrict__ row_ptr, int* __restrict__ cursor, int N){
  __shared__ int sd[256];
  int t=threadIdx.x;
  int base = blockIdx.x*1024 + t*4;
  int v[4]; int s=0;
  #pragma unroll
  for (int j=0;j<4;j++){ int i=base+j; v[j]=(i<N)?counts[i]:0; s+=v[j]; }
  sd[t]=s; __syncthreads();
  for (int off=1; off<256; off<<=1){
    int x = (t>=off)? sd[t-off] : 0;
    __syncthreads();
    sd[t] += x;
    __syncthreads();
  }
  int run = sd[t]-s + partials[blockIdx.x];
  #pragma unroll
  for (int j=0;j<4;j++){ int i=base+j; if (i<N){ row_ptr[i]=run; cursor[i]=run; } run+=v[j]; }
}

__global__ void k_scatter(const int* __restrict__ src, const int* __restrict__ dst,
                          int* __restrict__ cursor, int2* __restrict__ es, int E){
  int e = blockIdx.x*256+threadIdx.x;
  if (e<E){
    int d = dst[e];
    int p = atomicAdd(&cursor[d],1);
    int2 v; v.x = e; v.y = src[e];
    es[p] = v;
  }
}

// ---------- nf -> bf16 ----------
__global__ void k_cvt(const float* __restrict__ in, unsigned short* __restrict__ out, int n8){
  int i = blockIdx.x*256 + threadIdx.x;
  if (i >= n8) return;
  const float4* p = reinterpret_cast<const float4*>(in) + (size_t)i*2;
  float4 a = p[0], b = p[1];
  union { unsigned short s[8]; uint4 u; } r;
  r.s[0]=f2bf(a.x); r.s[1]=f2bf(a.y); r.s[2]=f2bf(a.z); r.s[3]=f2bf(a.w);
  r.s[4]=f2bf(b.x); r.s[5]=f2bf(b.y); r.s[6]=f2bf(b.z); r.s[7]=f2bf(b.w);
  reinterpret_cast<uint4*>(out)[i] = r.u;
}

// ---------- Mbf = bf16([W_ah | W_an*W_msg]) ; Wb = W_an * b_m ----------
__global__ void k_comb(const float* __restrict__ Wa, const float* __restrict__ Wm,
                       const float* __restrict__ bm, unsigned short* __restrict__ Mbf,
                       float* __restrict__ Wb){
  int o = blockIdx.x; int t = threadIdx.x;
  if (t < 128){
    Mbf[o*384+t] = f2bf(Wa[o*256+t]);
  } else {
    int i = t-128;
    float s=0.f;
    #pragma unroll 4
    for (int p=0;p<128;p++) s += Wa[o*256+128+p]*Wm[p*256+i];
    Mbf[o*384+t] = f2bf(s);
  }
  if (t==0){
    float s=0.f;
    for (int p=0;p<128;p++) s += Wa[o*256+128+p]*bm[p];
    Wb[o]=s;
  }
}

// ---------- per-node aggregation -> bf16 S + deg flag ----------
// one wave per node; 2 edges in flight per wave (32 lanes x float4 = 512B row),
// unroll-2 => 4 edges/iter; cross-half combine via shfl_xor(32).
__global__ void k_agg(const float* __restrict__ nf, const float* __restrict__ ef,
                      const int* __restrict__ rp, const int2* __restrict__ es,
                      unsigned short* __restrict__ Sbf, float* __restrict__ flagA, int N){
  int n = blockIdx.x*4 + (threadIdx.x>>6);
  if (n>=N) return;
  int lane = threadIdx.x & 63;
  int half = lane >> 5, l = lane & 31;
  int r0 = rp[n], r1 = rp[n+1];
  float dinv = 1.0f/fmaxf((float)(r1-r0),1.0f);
  const float4* nf4 = reinterpret_cast<const float4*>(nf);
  const float4* ef4 = reinterpret_cast<const float4*>(ef);
  float4 aH = make_float4(0.f,0.f,0.f,0.f), aE = make_float4(0.f,0.f,0.f,0.f);
  int j = r0;
  for (; j+4<=r1; j+=4){
    int2 p0 = es[j+half], p1 = es[j+2+half];
    float4 h0 = nf4[(size_t)p0.y*32 + l];
    float4 h1 = nf4[(size_t)p1.y*32 + l];
    float4 e0 = ef4[(size_t)p0.x*32 + l];
    float4 e1 = ef4[(size_t)p1.x*32 + l];
    aH.x += h0.x+h1.x; aH.y += h0.y+h1.y; aH.z += h0.z+h1.z; aH.w += h0.w+h1.w;
    aE.x += e0.x+e1.x; aE.y += e0.y+e1.y; aE.z += e0.z+e1.z; aE.w += e0.w+e1.w;
  }
  if (j+2<=r1){
    int2 p = es[j+half];
    float4 h = nf4[(size_t)p.y*32 + l];
    float4 e = ef4[(size_t)p.x*32 + l];
    aH.x+=h.x; aH.y+=h.y; aH.z+=h.z; aH.w+=h.w;
    aE.x+=e.x; aE.y+=e.y; aE.z+=e.z; aE.w+=e.w;
    j += 2;
  }
  if (j<r1 && half==0){
    int2 p = es[j];
    float4 h = nf4[(size_t)p.y*32 + l];
    float4 e = ef4[(size_t)p.x*32 + l];
    aH.x+=h.x; aH.y+=h.y; aH.z+=h.z; aH.w+=h.w;
    aE.x+=e.x; aE.y+=e.y; aE.z+=e.z; aE.w+=e.w;
  }
  aH.x += __shfl_xor(aH.x, 32); aH.y += __shfl_xor(aH.y, 32);
  aH.z += __shfl_xor(aH.z, 32); aH.w += __shfl_xor(aH.w, 32);
  aE.x += __shfl_xor(aE.x, 32); aE.y += __shfl_xor(aE.y, 32);
  aE.z += __shfl_xor(aE.z, 32); aE.w += __shfl_xor(aE.w, 32);
  ushort4 o;
  if (half==0){
    o.x=f2bf(aH.x*dinv); o.y=f2bf(aH.y*dinv); o.z=f2bf(aH.z*dinv); o.w=f2bf(aH.w*dinv);
    *reinterpret_cast<ushort4*>(Sbf + (size_t)n*256 + l*4) = o;
  } else {
    o.x=f2bf(aE.x*dinv); o.y=f2bf(aE.y*dinv); o.z=f2bf(aE.z*dinv); o.w=f2bf(aE.w*dinv);
    *reinterpret_cast<ushort4*>(Sbf + (size_t)n*256 + 128 + l*4) = o;
  }
  if (lane==0) flagA[n] = (r1>r0) ? 1.0f : 0.0f;
}

// ---------- new_h = relu([nf|S]_bf16 * Mbf^T + ba + flag*Wb), MFMA ----------
__global__ __launch_bounds__(256) void k_gemm(
    const unsigned short* __restrict__ nfb, const unsigned short* __restrict__ Sbf,
    const unsigned short* __restrict__ Mbf, const float* __restrict__ ba,
    const float* __restrict__ Wb, const float* __restrict__ flagA,
    float* __restrict__ outH, int N)
{
  __shared__ __align__(16) unsigned short As[128*32];
  __shared__ __align__(16) unsigned short Bs[128*32];
  int tid = threadIdx.x;
  int lane = tid & 63;
  int w = tid >> 6;
  int wr = w >> 1, wc = w & 1;
  int bn = blockIdx.x * 128;

  f32x4 acc[4][4];
  #pragma unroll
  for (int i=0;i<4;i++)
    #pragma unroll
    for (int j=0;j<4;j++) acc[i][j] = (f32x4){0.f,0.f,0.f,0.f};

  int lr = lane >> 2;
  int lb = (lane & 3) * 16;

  for (int kb = 0; kb < 384; kb += 32){
    #pragma unroll
    for (int c = 0; c < 2; c++){
      int rbase = w*32 + c*16;
      int row = rbase + lr;
      int n = bn + row; if (n >= N) n = N-1;
      const char* g;
      if (kb < 128) g = (const char*)nfb + (size_t)n*256 + (size_t)kb*2 + lb;
      else          g = (const char*)Sbf + (size_t)n*512 + (size_t)(kb-128)*2 + lb;
      gload_lds16(g, &As[rbase*32]);
      const char* gm = (const char*)Mbf + (size_t)row*768 + (size_t)kb*2 + lb;
      gload_lds16(gm, &Bs[rbase*32]);
    }
    __syncthreads();
    s16x8 af[4], bfr[4];
    int kg = (lane>>4)*8;
    #pragma unroll
    for (int bi=0;bi<4;bi++)
      af[bi] = *reinterpret_cast<const s16x8*>(&As[(wr*64 + bi*16 + (lane&15))*32 + kg]);
    #pragma unroll
    for (int bj=0;bj<4;bj++)
      bfr[bj] = *reinterpret_cast<const s16x8*>(&Bs[(wc*64 + bj*16 + (lane&15))*32 + kg]);
    #pragma unroll
    for (int bi=0;bi<4;bi++)
      #pragma unroll
      for (int bj=0;bj<4;bj++)
        acc[bi][bj] = __builtin_amdgcn_mfma_f32_16x16x32_bf16(af[bi], bfr[bj], acc[bi][bj], 0, 0, 0);
    __syncthreads();
  }

  float bav[4], wbv[4];
  #pragma unroll
  for (int bj=0;bj<4;bj++){
    int col = wc*64 + bj*16 + (lane&15);
    bav[bj] = ba[col]; wbv[bj] = Wb[col];
  }
  #pragma unroll
  for (int bi=0;bi<4;bi++){
    int rb = bn + wr*64 + bi*16 + (lane>>4)*4;
    #pragma unroll
    for (int r=0;r<4;r++){
      int row = rb + r;
      if (row < N){
        float fl = flagA[row];
        #pragma unroll
        for (int bj=0;bj<4;bj++){
          int col = wc*64 + bj*16 + (lane&15);
          float v = acc[bi][bj][r] + bav[bj] + fl*wbv[bj];
          outH[(size_t)row*128 + col] = fmaxf(v, 0.f);
        }
      }
    }
  }
}

// ---------- new_e in EDGE order: streaming coalesced writes, L3-hit gathers ----------
__global__ void k_edge(const int* __restrict__ src, const int* __restrict__ dst,
                       const float* __restrict__ H, float* __restrict__ NE, int E){
  int t = threadIdx.x;
  int e = blockIdx.x*8 + (t>>5);
  if (e>=E) return;
  int l = t & 31;
  const float4* Hs = reinterpret_cast<const float4*>(H + (size_t)src[e]*D);
  const float4* Hd = reinterpret_cast<const float4*>(H + (size_t)dst[e]*D);
  float4 a = Hs[l], b = Hd[l];
  float4 r;
  r.x = 0.5f*(a.x+b.x); r.y = 0.5f*(a.y+b.y);
  r.z = 0.5f*(a.z+b.z); r.w = 0.5f*(a.w+b.w);
  reinterpret_cast<float4*>(NE + (size_t)e*D)[l] = r;
}

extern "C" void kernel_launch(void* const* d_in, const int* in_sizes, int n_in,
                              void* d_out, int out_size, void* d_ws, size_t ws_size,
                              hipStream_t stream)
{
  const float* nf  = (const float*)d_in[0];
  const float* ef  = (const float*)d_in[1];
  const int*   src = (const int*)d_in[2];
  const int*   dst = (const int*)d_in[3];
  const float* Wm  = (const float*)d_in[4];
  const float* bm  = (const float*)d_in[5];
  const float* Wa  = (const float*)d_in[6];
  const float* bap = (const float*)d_in[7];
  int N = in_sizes[0]/D;
  int E = in_sizes[2];
  float* outH = (float*)d_out;
  float* outE = (float*)d_out + (size_t)N*D;

  size_t off = 0;
  auto alloc = [&](size_t bytes){ size_t o = off; off = (off + bytes + 255) & ~(size_t)255; return o; };
  size_t o_counts = alloc((size_t)N*4);
  size_t o_rp     = alloc((size_t)(N+1)*4);
  size_t o_part   = alloc(1024*4);
  size_t o_cur    = alloc((size_t)N*4);
  size_t o_es     = alloc((size_t)E*8);
  size_t o_M      = alloc((size_t)128*384*2);
  size_t o_wb     = alloc(128*4);
  size_t o_S      = alloc((size_t)N*256*2);
  size_t o_nfb    = alloc((size_t)N*128*2);
  size_t o_flag   = alloc((size_t)N*4);
  size_t need = off;
  bool ws_ok = (ws_size >= need);
  char* base = ws_ok ? (char*)d_ws : (char*)(void*)outE;

  int* counts  = (int*)(base + o_counts);
  int* row_ptr = (int*)(base + o_rp);
  int* partials= (int*)(base + o_part);
  int* cursor  = (int*)(base + o_cur);
  int2* es     = (int2*)(base + o_es);
  unsigned short* Mbf = (unsigned short*)(base + o_M);
  float* Wb    = (float*)(base + o_wb);
  unsigned short* Sbf = (unsigned short*)(base + o_S);
  unsigned short* nfb = (unsigned short*)(base + o_nfb);
  float* flagA = (float*)(base + o_flag);

  hipMemsetAsync(counts, 0, (size_t)N*4, stream);

  int NB = (N + 1023)/1024;
  k_hist   <<<(E+255)/256, 256, 0, stream>>>(dst, counts, E);
  k_scan1  <<<NB, 256, 0, stream>>>(counts, partials, N);
  k_scan2  <<<1, 1024, 0, stream>>>(partials, row_ptr, NB, N);
  k_scan3  <<<NB, 256, 0, stream>>>(counts, partials, row_ptr, cursor, N);
  k_scatter<<<(E+255)/256, 256, 0, stream>>>(src, dst, cursor, es, E);
  k_comb   <<<128, 384, 0, stream>>>(Wa, Wm, bm, Mbf, Wb);
  k_cvt    <<<(N*16 + 255)/256, 256, 0, stream>>>(nf, nfb, N*16);
  k_agg    <<<(N+3)/4, 256, 0, stream>>>(nf, ef, row_ptr, es, Sbf, flagA, N);
  k_gemm   <<<(N+127)/128, 256, 0, stream>>>(nfb, Sbf, Mbf, bap, Wb, flagA, outH, N);
  k_edge   <<<(E+7)/8, 256, 0, stream>>>(src, dst, outH, outE, E);
}

// Round 6
// 436.479 us; speedup vs baseline: 1.0581x; 1.0581x over previous
//
#include <hip/hip_runtime.h>

#define D 128

typedef __attribute__((ext_vector_type(4))) float f32x4;
typedef __attribute__((ext_vector_type(8))) short s16x8;

__device__ inline unsigned short f2bf(float x){
  unsigned u = __builtin_bit_cast(unsigned, x);
  u += 0x7FFFu + ((u>>16)&1u);
  return (unsigned short)(u>>16);
}

__device__ inline void gload_lds16(const void* g, void* l){
  __builtin_amdgcn_global_load_lds(
      (const __attribute__((address_space(1))) void*)g,
      (__attribute__((address_space(3))) void*)l, 16, 0, 0);
}

// ---------- CSR build ----------
__global__ void k_hist(const int* __restrict__ dst, int* __restrict__ counts, int E){
  int e = blockIdx.x*256 + threadIdx.x;
  if (e < E) atomicAdd(&counts[dst[e]], 1);
}

__global__ void k_scan1(const int* __restrict__ counts, int* __restrict__ partials, int N){
  __shared__ int sd[256];
  int t = threadIdx.x;
  int base = blockIdx.x*1024 + t*4;
  int s = 0;
  #pragma unroll
  for (int j=0;j<4;j++){ int i=base+j; s += (i<N)?counts[i]:0; }
  sd[t]=s; __syncthreads();
  for (int off=128; off>0; off>>=1){ if (t<off) sd[t]+=sd[t+off]; __syncthreads(); }
  if (t==0) partials[blockIdx.x]=sd[0];
}

__global__ void k_scan2(int* __restrict__ partials, int* __restrict__ row_ptr, int nb, int N){
  __shared__ int sd[1024];
  int t = threadIdx.x;
  if (nb <= 1024){
    int v = (t < nb) ? partials[t] : 0;
    sd[t] = v;
    __syncthreads();
    #pragma unroll
    for (int off=1; off<1024; off<<=1){
      int x = (t >= off) ? sd[t-off] : 0;
      __syncthreads();
      sd[t] += x;
      __syncthreads();
    }
    if (t < nb) partials[t] = sd[t] - v;
    if (t == 1023) row_ptr[N] = sd[1023];
  } else if (t == 0){
    int run=0;
    for (int b=0;b<nb;b++){ int v=partials[b]; partials[b]=run; run+=v; }
    row_ptr[N]=run;
  }
}

__global__ void k_scan3(const int* __restrict__ counts, const int* __restrict__ partials,
                        int* __restrict__ row_ptr, int* __restrict__ cursor, int N){
  __shared__ int sd[256];
  int t=threadIdx.x;
  int base = blockIdx.x*1024 + t*4;
  int v[4]; int s=0;
  #pragma unroll
  for (int j=0;j<4;j++){ int i=base+j; v[j]=(i<N)?counts[i]:0; s+=v[j]; }
  sd[t]=s; __syncthreads();
  for (int off=1; off<256; off<<=1){
    int x = (t>=off)? sd[t-off] : 0;
    __syncthreads();
    sd[t] += x;
    __syncthreads();
  }
  int run = sd[t]-s + partials[blockIdx.x];
  #pragma unroll
  for (int j=0;j<4;j++){ int i=base+j; if (i<N){ row_ptr[i]=run; cursor[i]=run; } run+=v[j]; }
}

__global__ void k_scatter(const int* __restrict__ src, const int* __restrict__ dst,
                          int* __restrict__ cursor, int2* __restrict__ es, int E){
  int e = blockIdx.x*256+threadIdx.x;
  if (e<E){
    int d = dst[e];
    int p = atomicAdd(&cursor[d],1);
    int2 v; v.x = e; v.y = src[e];
    es[p] = v;
  }
}

// ---------- nf -> bf16 ----------
__global__ void k_cvt(const float* __restrict__ in, unsigned short* __restrict__ out, int n8){
  int i = blockIdx.x*256 + threadIdx.x;
  if (i >= n8) return;
  const float4* p = reinterpret_cast<const float4*>(in) + (size_t)i*2;
  float4 a = p[0], b = p[1];
  union { unsigned short s[8]; uint4 u; } r;
  r.s[0]=f2bf(a.x); r.s[1]=f2bf(a.y); r.s[2]=f2bf(a.z); r.s[3]=f2bf(a.w);
  r.s[4]=f2bf(b.x); r.s[5]=f2bf(b.y); r.s[6]=f2bf(b.z); r.s[7]=f2bf(b.w);
  reinterpret_cast<uint4*>(out)[i] = r.u;
}

// ---------- Mbf = bf16([W_ah | W_an*W_msg]) ; Wb = W_an * b_m ----------
__global__ void k_comb(const float* __restrict__ Wa, const float* __restrict__ Wm,
                       const float* __restrict__ bm, unsigned short* __restrict__ Mbf,
                       float* __restrict__ Wb){
  int o = blockIdx.x; int t = threadIdx.x;
  if (t < 128){
    Mbf[o*384+t] = f2bf(Wa[o*256+t]);
  } else {
    int i = t-128;
    float s=0.f;
    #pragma unroll 4
    for (int p=0;p<128;p++) s += Wa[o*256+128+p]*Wm[p*256+i];
    Mbf[o*384+t] = f2bf(s);
  }
  if (t==0){
    float s=0.f;
    for (int p=0;p<128;p++) s += Wa[o*256+128+p]*bm[p];
    Wb[o]=s;
  }
}

// ---------- per-node aggregation -> bf16 S + deg flag (R3: unroll-4 float2) ----------
__global__ void k_agg(const float* __restrict__ nf, const float* __restrict__ ef,
                      const int* __restrict__ rp, const int2* __restrict__ es,
                      unsigned short* __restrict__ Sbf, float* __restrict__ flagA, int N){
  int n = blockIdx.x*4 + (threadIdx.x>>6);
  int lane = threadIdx.x & 63;
  if (n>=N) return;
  int r0 = rp[n], r1 = rp[n+1];
  float dinv = 1.0f/fmaxf((float)(r1-r0),1.0f);
  float aH0=0.f,aH1=0.f,aE0=0.f,aE1=0.f;
  int j = r0;
  for (; j+4<=r1; j+=4){
    int2 p0=es[j], p1=es[j+1], p2=es[j+2], p3=es[j+3];
    float2 h0 = reinterpret_cast<const float2*>(nf + (size_t)p0.y*D)[lane];
    float2 h1 = reinterpret_cast<const float2*>(nf + (size_t)p1.y*D)[lane];
    float2 h2 = reinterpret_cast<const float2*>(nf + (size_t)p2.y*D)[lane];
    float2 h3 = reinterpret_cast<const float2*>(nf + (size_t)p3.y*D)[lane];
    float2 e0 = reinterpret_cast<const float2*>(ef + (size_t)p0.x*D)[lane];
    float2 e1 = reinterpret_cast<const float2*>(ef + (size_t)p1.x*D)[lane];
    float2 e2 = reinterpret_cast<const float2*>(ef + (size_t)p2.x*D)[lane];
    float2 e3 = reinterpret_cast<const float2*>(ef + (size_t)p3.x*D)[lane];
    aH0 += (h0.x+h1.x)+(h2.x+h3.x);
    aH1 += (h0.y+h1.y)+(h2.y+h3.y);
    aE0 += (e0.x+e1.x)+(e2.x+e3.x);
    aE1 += (e0.y+e1.y)+(e2.y+e3.y);
  }
  for (; j<r1; j++){
    int2 p = es[j];
    float2 h2 = reinterpret_cast<const float2*>(nf + (size_t)p.y*D)[lane];
    float2 e2 = reinterpret_cast<const float2*>(ef + (size_t)p.x*D)[lane];
    aH0+=h2.x; aH1+=h2.y; aE0+=e2.x; aE1+=e2.y;
  }
  ushort2* So = reinterpret_cast<ushort2*>(Sbf + (size_t)n*256);
  ushort2 th; th.x = f2bf(aH0*dinv); th.y = f2bf(aH1*dinv);
  ushort2 te; te.x = f2bf(aE0*dinv); te.y = f2bf(aE1*dinv);
  So[lane]    = th;
  So[64+lane] = te;
  if (lane==0) flagA[n] = (r1>r0) ? 1.0f : 0.0f;
}

// ---------- new_h = relu([nf|S]_bf16 * Mbf^T + ba + flag*Wb), MFMA ----------
__global__ __launch_bounds__(256) void k_gemm(
    const unsigned short* __restrict__ nfb, const unsigned short* __restrict__ Sbf,
    const unsigned short* __restrict__ Mbf, const float* __restrict__ ba,
    const float* __restrict__ Wb, const float* __restrict__ flagA,
    float* __restrict__ outH, int N)
{
  __shared__ __align__(16) unsigned short As[128*32];
  __shared__ __align__(16) unsigned short Bs[128*32];
  int tid = threadIdx.x;
  int lane = tid & 63;
  int w = tid >> 6;
  int wr = w >> 1, wc = w & 1;
  int bn = blockIdx.x * 128;

  f32x4 acc[4][4];
  #pragma unroll
  for (int i=0;i<4;i++)
    #pragma unroll
    for (int j=0;j<4;j++) acc[i][j] = (f32x4){0.f,0.f,0.f,0.f};

  int lr = lane >> 2;
  int lb = (lane & 3) * 16;

  for (int kb = 0; kb < 384; kb += 32){
    #pragma unroll
    for (int c = 0; c < 2; c++){
      int rbase = w*32 + c*16;
      int row = rbase + lr;
      int n = bn + row; if (n >= N) n = N-1;
      const char* g;
      if (kb < 128) g = (const char*)nfb + (size_t)n*256 + (size_t)kb*2 + lb;
      else          g = (const char*)Sbf + (size_t)n*512 + (size_t)(kb-128)*2 + lb;
      gload_lds16(g, &As[rbase*32]);
      const char* gm = (const char*)Mbf + (size_t)row*768 + (size_t)kb*2 + lb;
      gload_lds16(gm, &Bs[rbase*32]);
    }
    __syncthreads();
    s16x8 af[4], bfr[4];
    int kg = (lane>>4)*8;
    #pragma unroll
    for (int bi=0;bi<4;bi++)
      af[bi] = *reinterpret_cast<const s16x8*>(&As[(wr*64 + bi*16 + (lane&15))*32 + kg]);
    #pragma unroll
    for (int bj=0;bj<4;bj++)
      bfr[bj] = *reinterpret_cast<const s16x8*>(&Bs[(wc*64 + bj*16 + (lane&15))*32 + kg]);
    #pragma unroll
    for (int bi=0;bi<4;bi++)
      #pragma unroll
      for (int bj=0;bj<4;bj++)
        acc[bi][bj] = __builtin_amdgcn_mfma_f32_16x16x32_bf16(af[bi], bfr[bj], acc[bi][bj], 0, 0, 0);
    __syncthreads();
  }

  float bav[4], wbv[4];
  #pragma unroll
  for (int bj=0;bj<4;bj++){
    int col = wc*64 + bj*16 + (lane&15);
    bav[bj] = ba[col]; wbv[bj] = Wb[col];
  }
  #pragma unroll
  for (int bi=0;bi<4;bi++){
    int rb = bn + wr*64 + bi*16 + (lane>>4)*4;
    #pragma unroll
    for (int r=0;r<4;r++){
      int row = rb + r;
      if (row < N){
        float fl = flagA[row];
        #pragma unroll
        for (int bj=0;bj<4;bj++){
          int col = wc*64 + bj*16 + (lane&15);
          float v = acc[bi][bj][r] + bav[bj] + fl*wbv[bj];
          outH[(size_t)row*128 + col] = fmaxf(v, 0.f);
        }
      }
    }
  }
}

// ---------- new_e in CSR order, v2: 2 edges in flight, 32-lane float4 ----------
// per iter: 2 es loads, 4 gathers, 4 writes -> 4 edges (half the instrs of v1).
// identical arithmetic to reference order: 0.5*(hn + hs).
__global__ void k_edge_csr(const float* __restrict__ H, const int* __restrict__ rp,
                           const int2* __restrict__ es, float* __restrict__ NE, int N){
  int n = blockIdx.x*4 + (threadIdx.x>>6);
  if (n>=N) return;
  int lane = threadIdx.x & 63;
  int half = lane >> 5, l = lane & 31;
  int r0 = rp[n], r1 = rp[n+1];
  const float4* H4 = reinterpret_cast<const float4*>(H);
  float4* NE4 = reinterpret_cast<float4*>(NE);
  float4 hn = H4[(size_t)n*32 + l];
  int j = r0;
  for (; j+4<=r1; j+=4){
    int2 p0 = es[j+half], p1 = es[j+2+half];
    float4 a0 = H4[(size_t)p0.y*32 + l];
    float4 a1 = H4[(size_t)p1.y*32 + l];
    float4 o0, o1;
    o0.x=0.5f*(hn.x+a0.x); o0.y=0.5f*(hn.y+a0.y); o0.z=0.5f*(hn.z+a0.z); o0.w=0.5f*(hn.w+a0.w);
    o1.x=0.5f*(hn.x+a1.x); o1.y=0.5f*(hn.y+a1.y); o1.z=0.5f*(hn.z+a1.z); o1.w=0.5f*(hn.w+a1.w);
    NE4[(size_t)p0.x*32 + l] = o0;
    NE4[(size_t)p1.x*32 + l] = o1;
  }
  if (j+2<=r1){
    int2 p = es[j+half];
    float4 a = H4[(size_t)p.y*32 + l];
    float4 o;
    o.x=0.5f*(hn.x+a.x); o.y=0.5f*(hn.y+a.y); o.z=0.5f*(hn.z+a.z); o.w=0.5f*(hn.w+a.w);
    NE4[(size_t)p.x*32 + l] = o;
    j += 2;
  }
  if (j<r1 && half==0){
    int2 p = es[j];
    float4 a = H4[(size_t)p.y*32 + l];
    float4 o;
    o.x=0.5f*(hn.x+a.x); o.y=0.5f*(hn.y+a.y); o.z=0.5f*(hn.z+a.z); o.w=0.5f*(hn.w+a.w);
    NE4[(size_t)p.x*32 + l] = o;
  }
}

// fallback (workspace-in-output mode): edge-order version reading only inputs
__global__ void k_edge(const int* __restrict__ src, const int* __restrict__ dst,
                       const float* __restrict__ H, float* __restrict__ NE, int E){
  int t = threadIdx.x;
  int e = blockIdx.x*8 + (t>>5);
  if (e>=E) return;
  int l = t & 31;
  const float4* Hs = reinterpret_cast<const float4*>(H + (size_t)src[e]*D);
  const float4* Hd = reinterpret_cast<const float4*>(H + (size_t)dst[e]*D);
  float4 a = Hs[l], b = Hd[l];
  float4 r;
  r.x = 0.5f*(a.x+b.x); r.y = 0.5f*(a.y+b.y);
  r.z = 0.5f*(a.z+b.z); r.w = 0.5f*(a.w+b.w);
  reinterpret_cast<float4*>(NE + (size_t)e*D)[l] = r;
}

extern "C" void kernel_launch(void* const* d_in, const int* in_sizes, int n_in,
                              void* d_out, int out_size, void* d_ws, size_t ws_size,
                              hipStream_t stream)
{
  const float* nf  = (const float*)d_in[0];
  const float* ef  = (const float*)d_in[1];
  const int*   src = (const int*)d_in[2];
  const int*   dst = (const int*)d_in[3];
  const float* Wm  = (const float*)d_in[4];
  const float* bm  = (const float*)d_in[5];
  const float* Wa  = (const float*)d_in[6];
  const float* bap = (const float*)d_in[7];
  int N = in_sizes[0]/D;
  int E = in_sizes[2];
  float* outH = (float*)d_out;
  float* outE = (float*)d_out + (size_t)N*D;

  size_t off = 0;
  auto alloc = [&](size_t bytes){ size_t o = off; off = (off + bytes + 255) & ~(size_t)255; return o; };
  size_t o_counts = alloc((size_t)N*4);
  size_t o_rp     = alloc((size_t)(N+1)*4);
  size_t o_part   = alloc(1024*4);
  size_t o_cur    = alloc((size_t)N*4);
  size_t o_es     = alloc((size_t)E*8);
  size_t o_M      = alloc((size_t)128*384*2);
  size_t o_wb     = alloc(128*4);
  size_t o_S      = alloc((size_t)N*256*2);
  size_t o_nfb    = alloc((size_t)N*128*2);
  size_t o_flag   = alloc((size_t)N*4);
  size_t need = off;
  bool ws_ok = (ws_size >= need);
  char* base = ws_ok ? (char*)d_ws : (char*)(void*)outE;

  int* counts  = (int*)(base + o_counts);
  int* row_ptr = (int*)(base + o_rp);
  int* partials= (int*)(base + o_part);
  int* cursor  = (int*)(base + o_cur);
  int2* es     = (int2*)(base + o_es);
  unsigned short* Mbf = (unsigned short*)(base + o_M);
  float* Wb    = (float*)(base + o_wb);
  unsigned short* Sbf = (unsigned short*)(base + o_S);
  unsigned short* nfb = (unsigned short*)(base + o_nfb);
  float* flagA = (float*)(base + o_flag);

  hipMemsetAsync(counts, 0, (size_t)N*4, stream);

  int NB = (N + 1023)/1024;
  k_hist   <<<(E+255)/256, 256, 0, stream>>>(dst, counts, E);
  k_scan1  <<<NB, 256, 0, stream>>>(counts, partials, N);
  k_scan2  <<<1, 1024, 0, stream>>>(partials, row_ptr, NB, N);
  k_scan3  <<<NB, 256, 0, stream>>>(counts, partials, row_ptr, cursor, N);
  k_scatter<<<(E+255)/256, 256, 0, stream>>>(src, dst, cursor, es, E);
  k_comb   <<<128, 384, 0, stream>>>(Wa, Wm, bm, Mbf, Wb);
  k_cvt    <<<(N*16 + 255)/256, 256, 0, stream>>>(nf, nfb, N*16);
  k_agg    <<<(N+3)/4, 256, 0, stream>>>(nf, ef, row_ptr, es, Sbf, flagA, N);
  k_gemm   <<<(N+127)/128, 256, 0, stream>>>(nfb, Sbf, Mbf, bap, Wb, flagA, outH, N);
  if (ws_ok)
    k_edge_csr<<<(N+3)/4, 256, 0, stream>>>(outH, row_ptr, es, outE, N);
  else
    k_edge    <<<(E+7)/8, 256, 0, stream>>>(src, dst, outH, outE, E);
}

// Round 7
// 415.350 us; speedup vs baseline: 1.1119x; 1.0509x over previous
//
#include <hip/hip_runtime.h>

#define D 128

typedef __attribute__((ext_vector_type(4))) float f32x4;
typedef __attribute__((ext_vector_type(8))) short s16x8;

__device__ inline unsigned short f2bf(float x){
  unsigned u = __builtin_bit_cast(unsigned, x);
  u += 0x7FFFu + ((u>>16)&1u);
  return (unsigned short)(u>>16);
}
__device__ inline float bf2f(unsigned short u){
  return __builtin_bit_cast(float, (unsigned)u << 16);
}

__device__ inline void gload_lds16(const void* g, void* l){
  __builtin_amdgcn_global_load_lds(
      (const __attribute__((address_space(1))) void*)g,
      (__attribute__((address_space(3))) void*)l, 16, 0, 0);
}

// ---------- CSR build ----------
__global__ void k_hist(const int* __restrict__ dst, int* __restrict__ counts, int E){
  int e = blockIdx.x*256 + threadIdx.x;
  if (e < E) atomicAdd(&counts[dst[e]], 1);
}

__global__ void k_scan1(const int* __restrict__ counts, int* __restrict__ partials, int N){
  __shared__ int sd[256];
  int t = threadIdx.x;
  int base = blockIdx.x*1024 + t*4;
  int s = 0;
  #pragma unroll
  for (int j=0;j<4;j++){ int i=base+j; s += (i<N)?counts[i]:0; }
  sd[t]=s; __syncthreads();
  for (int off=128; off>0; off>>=1){ if (t<off) sd[t]+=sd[t+off]; __syncthreads(); }
  if (t==0) partials[blockIdx.x]=sd[0];
}

__global__ void k_scan2(int* __restrict__ partials, int* __restrict__ row_ptr, int nb, int N){
  __shared__ int sd[1024];
  int t = threadIdx.x;
  if (nb <= 1024){
    int v = (t < nb) ? partials[t] : 0;
    sd[t] = v;
    __syncthreads();
    #pragma unroll
    for (int off=1; off<1024; off<<=1){
      int x = (t >= off) ? sd[t-off] : 0;
      __syncthreads();
      sd[t] += x;
      __syncthreads();
    }
    if (t < nb) partials[t] = sd[t] - v;
    if (t == 1023) row_ptr[N] = sd[1023];
  } else if (t == 0){
    int run=0;
    for (int b=0;b<nb;b++){ int v=partials[b]; partials[b]=run; run+=v; }
    row_ptr[N]=run;
  }
}

__global__ void k_scan3(const int* __restrict__ counts, const int* __restrict__ partials,
                        int* __restrict__ row_ptr, int* __restrict__ cursor, int N){
  __shared__ int sd[256];
  int t=threadIdx.x;
  int base = blockIdx.x*1024 + t*4;
  int v[4]; int s=0;
  #pragma unroll
  for (int j=0;j<4;j++){ int i=base+j; v[j]=(i<N)?counts[i]:0; s+=v[j]; }
  sd[t]=s; __syncthreads();
  for (int off=1; off<256; off<<=1){
    int x = (t>=off)? sd[t-off] : 0;
    __syncthreads();
    sd[t] += x;
    __syncthreads();
  }
  int run = sd[t]-s + partials[blockIdx.x];
  #pragma unroll
  for (int j=0;j<4;j++){ int i=base+j; if (i<N){ row_ptr[i]=run; cursor[i]=run; } run+=v[j]; }
}

__global__ void k_scatter(const int* __restrict__ src, const int* __restrict__ dst,
                          int* __restrict__ cursor, int2* __restrict__ es, int E){
  int e = blockIdx.x*256+threadIdx.x;
  if (e<E){
    int d = dst[e];
    int p = atomicAdd(&cursor[d],1);
    int2 v; v.x = e; v.y = src[e];
    es[p] = v;
  }
}

// ---------- nf -> bf16 ----------
__global__ void k_cvt(const float* __restrict__ in, unsigned short* __restrict__ out, int n8){
  int i = blockIdx.x*256 + threadIdx.x;
  if (i >= n8) return;
  const float4* p = reinterpret_cast<const float4*>(in) + (size_t)i*2;
  float4 a = p[0], b = p[1];
  union { unsigned short s[8]; uint4 u; } r;
  r.s[0]=f2bf(a.x); r.s[1]=f2bf(a.y); r.s[2]=f2bf(a.z); r.s[3]=f2bf(a.w);
  r.s[4]=f2bf(b.x); r.s[5]=f2bf(b.y); r.s[6]=f2bf(b.z); r.s[7]=f2bf(b.w);
  reinterpret_cast<uint4*>(out)[i] = r.u;
}

// ---------- Mbf = bf16([W_ah | W_an*W_msg]) ; Wb = W_an * b_m ----------
__global__ void k_comb(const float* __restrict__ Wa, const float* __restrict__ Wm,
                       const float* __restrict__ bm, unsigned short* __restrict__ Mbf,
                       float* __restrict__ Wb){
  int o = blockIdx.x; int t = threadIdx.x;
  if (t < 128){
    Mbf[o*384+t] = f2bf(Wa[o*256+t]);
  } else {
    int i = t-128;
    float s=0.f;
    #pragma unroll 4
    for (int p=0;p<128;p++) s += Wa[o*256+128+p]*Wm[p*256+i];
    Mbf[o*384+t] = f2bf(s);
  }
  if (t==0){
    float s=0.f;
    for (int p=0;p<128;p++) s += Wa[o*256+128+p]*bm[p];
    Wb[o]=s;
  }
}

// ---------- per-node aggregation -> bf16 S + deg flag ----------
// h-gathers from bf16 nfb (256B rows): halves random-gather traffic.
__global__ void k_agg(const unsigned short* __restrict__ nfb, const float* __restrict__ ef,
                      const int* __restrict__ rp, const int2* __restrict__ es,
                      unsigned short* __restrict__ Sbf, float* __restrict__ flagA, int N){
  int n = blockIdx.x*4 + (threadIdx.x>>6);
  int lane = threadIdx.x & 63;
  if (n>=N) return;
  int r0 = rp[n], r1 = rp[n+1];
  float dinv = 1.0f/fmaxf((float)(r1-r0),1.0f);
  float aH0=0.f,aH1=0.f,aE0=0.f,aE1=0.f;
  int j = r0;
  for (; j+4<=r1; j+=4){
    int2 p0=es[j], p1=es[j+1], p2=es[j+2], p3=es[j+3];
    ushort2 h0 = reinterpret_cast<const ushort2*>(nfb + (size_t)p0.y*D)[lane];
    ushort2 h1 = reinterpret_cast<const ushort2*>(nfb + (size_t)p1.y*D)[lane];
    ushort2 h2 = reinterpret_cast<const ushort2*>(nfb + (size_t)p2.y*D)[lane];
    ushort2 h3 = reinterpret_cast<const ushort2*>(nfb + (size_t)p3.y*D)[lane];
    float2 e0 = reinterpret_cast<const float2*>(ef + (size_t)p0.x*D)[lane];
    float2 e1 = reinterpret_cast<const float2*>(ef + (size_t)p1.x*D)[lane];
    float2 e2 = reinterpret_cast<const float2*>(ef + (size_t)p2.x*D)[lane];
    float2 e3 = reinterpret_cast<const float2*>(ef + (size_t)p3.x*D)[lane];
    aH0 += (bf2f(h0.x)+bf2f(h1.x))+(bf2f(h2.x)+bf2f(h3.x));
    aH1 += (bf2f(h0.y)+bf2f(h1.y))+(bf2f(h2.y)+bf2f(h3.y));
    aE0 += (e0.x+e1.x)+(e2.x+e3.x);
    aE1 += (e0.y+e1.y)+(e2.y+e3.y);
  }
  for (; j<r1; j++){
    int2 p = es[j];
    ushort2 h = reinterpret_cast<const ushort2*>(nfb + (size_t)p.y*D)[lane];
    float2 e2 = reinterpret_cast<const float2*>(ef + (size_t)p.x*D)[lane];
    aH0+=bf2f(h.x); aH1+=bf2f(h.y); aE0+=e2.x; aE1+=e2.y;
  }
  ushort2* So = reinterpret_cast<ushort2*>(Sbf + (size_t)n*256);
  ushort2 th; th.x = f2bf(aH0*dinv); th.y = f2bf(aH1*dinv);
  ushort2 te; te.x = f2bf(aE0*dinv); te.y = f2bf(aE1*dinv);
  So[lane]    = th;
  So[64+lane] = te;
  if (lane==0) flagA[n] = (r1>r0) ? 1.0f : 0.0f;
}

// ---------- new_h = relu([nf|S]_bf16 * Mbf^T + ba + flag*Wb), MFMA ----------
// epilogue writes f32 H (output) and bf16 Hb (for the edge kernel's gathers)
__global__ __launch_bounds__(256) void k_gemm(
    const unsigned short* __restrict__ nfb, const unsigned short* __restrict__ Sbf,
    const unsigned short* __restrict__ Mbf, const float* __restrict__ ba,
    const float* __restrict__ Wb, const float* __restrict__ flagA,
    float* __restrict__ outH, unsigned short* __restrict__ Hb, int N)
{
  __shared__ __align__(16) unsigned short As[128*32];
  __shared__ __align__(16) unsigned short Bs[128*32];
  int tid = threadIdx.x;
  int lane = tid & 63;
  int w = tid >> 6;
  int wr = w >> 1, wc = w & 1;
  int bn = blockIdx.x * 128;

  f32x4 acc[4][4];
  #pragma unroll
  for (int i=0;i<4;i++)
    #pragma unroll
    for (int j=0;j<4;j++) acc[i][j] = (f32x4){0.f,0.f,0.f,0.f};

  int lr = lane >> 2;
  int lb = (lane & 3) * 16;

  for (int kb = 0; kb < 384; kb += 32){
    #pragma unroll
    for (int c = 0; c < 2; c++){
      int rbase = w*32 + c*16;
      int row = rbase + lr;
      int n = bn + row; if (n >= N) n = N-1;
      const char* g;
      if (kb < 128) g = (const char*)nfb + (size_t)n*256 + (size_t)kb*2 + lb;
      else          g = (const char*)Sbf + (size_t)n*512 + (size_t)(kb-128)*2 + lb;
      gload_lds16(g, &As[rbase*32]);
      const char* gm = (const char*)Mbf + (size_t)row*768 + (size_t)kb*2 + lb;
      gload_lds16(gm, &Bs[rbase*32]);
    }
    __syncthreads();
    s16x8 af[4], bfr[4];
    int kg = (lane>>4)*8;
    #pragma unroll
    for (int bi=0;bi<4;bi++)
      af[bi] = *reinterpret_cast<const s16x8*>(&As[(wr*64 + bi*16 + (lane&15))*32 + kg]);
    #pragma unroll
    for (int bj=0;bj<4;bj++)
      bfr[bj] = *reinterpret_cast<const s16x8*>(&Bs[(wc*64 + bj*16 + (lane&15))*32 + kg]);
    #pragma unroll
    for (int bi=0;bi<4;bi++)
      #pragma unroll
      for (int bj=0;bj<4;bj++)
        acc[bi][bj] = __builtin_amdgcn_mfma_f32_16x16x32_bf16(af[bi], bfr[bj], acc[bi][bj], 0, 0, 0);
    __syncthreads();
  }

  float bav[4], wbv[4];
  #pragma unroll
  for (int bj=0;bj<4;bj++){
    int col = wc*64 + bj*16 + (lane&15);
    bav[bj] = ba[col]; wbv[bj] = Wb[col];
  }
  #pragma unroll
  for (int bi=0;bi<4;bi++){
    int rb = bn + wr*64 + bi*16 + (lane>>4)*4;
    #pragma unroll
    for (int r=0;r<4;r++){
      int row = rb + r;
      if (row < N){
        float fl = flagA[row];
        #pragma unroll
        for (int bj=0;bj<4;bj++){
          int col = wc*64 + bj*16 + (lane&15);
          float v = fmaxf(acc[bi][bj][r] + bav[bj] + fl*wbv[bj], 0.f);
          outH[(size_t)row*128 + col] = v;
          Hb[(size_t)row*128 + col] = f2bf(v);
        }
      }
    }
  }
}

// ---------- new_e in CSR order from bf16 Hb gathers (256B rows) ----------
__global__ void k_edge_csr(const unsigned short* __restrict__ Hb, const int* __restrict__ rp,
                           const int2* __restrict__ es, float* __restrict__ NE, int N){
  int n = blockIdx.x*4 + (threadIdx.x>>6);
  if (n>=N) return;
  int lane = threadIdx.x & 63;
  int half = lane >> 5, l = lane & 31;
  int r0 = rp[n], r1 = rp[n+1];
  const ushort4* H4 = reinterpret_cast<const ushort4*>(Hb);
  float4* NE4 = reinterpret_cast<float4*>(NE);
  ushort4 hnu = H4[(size_t)n*32 + l];
  float4 hn = make_float4(bf2f(hnu.x), bf2f(hnu.y), bf2f(hnu.z), bf2f(hnu.w));
  int j = r0;
  for (; j+4<=r1; j+=4){
    int2 p0 = es[j+half], p1 = es[j+2+half];
    ushort4 u0 = H4[(size_t)p0.y*32 + l];
    ushort4 u1 = H4[(size_t)p1.y*32 + l];
    float4 o0, o1;
    o0.x=0.5f*(hn.x+bf2f(u0.x)); o0.y=0.5f*(hn.y+bf2f(u0.y));
    o0.z=0.5f*(hn.z+bf2f(u0.z)); o0.w=0.5f*(hn.w+bf2f(u0.w));
    o1.x=0.5f*(hn.x+bf2f(u1.x)); o1.y=0.5f*(hn.y+bf2f(u1.y));
    o1.z=0.5f*(hn.z+bf2f(u1.z)); o1.w=0.5f*(hn.w+bf2f(u1.w));
    NE4[(size_t)p0.x*32 + l] = o0;
    NE4[(size_t)p1.x*32 + l] = o1;
  }
  if (j+2<=r1){
    int2 p = es[j+half];
    ushort4 u = H4[(size_t)p.y*32 + l];
    float4 o;
    o.x=0.5f*(hn.x+bf2f(u.x)); o.y=0.5f*(hn.y+bf2f(u.y));
    o.z=0.5f*(hn.z+bf2f(u.z)); o.w=0.5f*(hn.w+bf2f(u.w));
    NE4[(size_t)p.x*32 + l] = o;
    j += 2;
  }
  if (j<r1 && half==0){
    int2 p = es[j];
    ushort4 u = H4[(size_t)p.y*32 + l];
    float4 o;
    o.x=0.5f*(hn.x+bf2f(u.x)); o.y=0.5f*(hn.y+bf2f(u.y));
    o.z=0.5f*(hn.z+bf2f(u.z)); o.w=0.5f*(hn.w+bf2f(u.w));
    NE4[(size_t)p.x*32 + l] = o;
  }
}

// fallback (workspace-in-output mode): edge-order version reading only f32 H
__global__ void k_edge(const int* __restrict__ src, const int* __restrict__ dst,
                       const float* __restrict__ H, float* __restrict__ NE, int E){
  int t = threadIdx.x;
  int e = blockIdx.x*8 + (t>>5);
  if (e>=E) return;
  int l = t & 31;
  const float4* Hs = reinterpret_cast<const float4*>(H + (size_t)src[e]*D);
  const float4* Hd = reinterpret_cast<const float4*>(H + (size_t)dst[e]*D);
  float4 a = Hs[l], b = Hd[l];
  float4 r;
  r.x = 0.5f*(a.x+b.x); r.y = 0.5f*(a.y+b.y);
  r.z = 0.5f*(a.z+b.z); r.w = 0.5f*(a.w+b.w);
  reinterpret_cast<float4*>(NE + (size_t)e*D)[l] = r;
}

extern "C" void kernel_launch(void* const* d_in, const int* in_sizes, int n_in,
                              void* d_out, int out_size, void* d_ws, size_t ws_size,
                              hipStream_t stream)
{
  const float* nf  = (const float*)d_in[0];
  const float* ef  = (const float*)d_in[1];
  const int*   src = (const int*)d_in[2];
  const int*   dst = (const int*)d_in[3];
  const float* Wm  = (const float*)d_in[4];
  const float* bm  = (const float*)d_in[5];
  const float* Wa  = (const float*)d_in[6];
  const float* bap = (const float*)d_in[7];
  int N = in_sizes[0]/D;
  int E = in_sizes[2];
  float* outH = (float*)d_out;
  float* outE = (float*)d_out + (size_t)N*D;

  size_t off = 0;
  auto alloc = [&](size_t bytes){ size_t o = off; off = (off + bytes + 255) & ~(size_t)255; return o; };
  size_t o_counts = alloc((size_t)N*4);
  size_t o_rp     = alloc((size_t)(N+1)*4);
  size_t o_part   = alloc(1024*4);
  size_t o_cur    = alloc((size_t)N*4);
  size_t o_es     = alloc((size_t)E*8);
  size_t o_M      = alloc((size_t)128*384*2);
  size_t o_wb     = alloc(128*4);
  size_t o_S      = alloc((size_t)N*256*2);
  size_t o_nfb    = alloc((size_t)N*128*2);
  size_t o_flag   = alloc((size_t)N*4);
  size_t o_hb     = alloc((size_t)N*128*2);
  size_t need = off;
  bool ws_ok = (ws_size >= need);
  char* base = ws_ok ? (char*)d_ws : (char*)(void*)outE;

  int* counts  = (int*)(base + o_counts);
  int* row_ptr = (int*)(base + o_rp);
  int* partials= (int*)(base + o_part);
  int* cursor  = (int*)(base + o_cur);
  int2* es     = (int2*)(base + o_es);
  unsigned short* Mbf = (unsigned short*)(base + o_M);
  float* Wb    = (float*)(base + o_wb);
  unsigned short* Sbf = (unsigned short*)(base + o_S);
  unsigned short* nfb = (unsigned short*)(base + o_nfb);
  float* flagA = (float*)(base + o_flag);
  unsigned short* Hb  = (unsigned short*)(base + o_hb);

  hipMemsetAsync(counts, 0, (size_t)N*4, stream);

  int NB = (N + 1023)/1024;
  k_hist   <<<(E+255)/256, 256, 0, stream>>>(dst, counts, E);
  k_scan1  <<<NB, 256, 0, stream>>>(counts, partials, N);
  k_scan2  <<<1, 1024, 0, stream>>>(partials, row_ptr, NB, N);
  k_scan3  <<<NB, 256, 0, stream>>>(counts, partials, row_ptr, cursor, N);
  k_scatter<<<(E+255)/256, 256, 0, stream>>>(src, dst, cursor, es, E);
  k_comb   <<<128, 384, 0, stream>>>(Wa, Wm, bm, Mbf, Wb);
  k_cvt    <<<(N*16 + 255)/256, 256, 0, stream>>>(nf, nfb, N*16);
  k_agg    <<<(N+3)/4, 256, 0, stream>>>(nfb, ef, row_ptr, es, Sbf, flagA, N);
  k_gemm   <<<(N+127)/128, 256, 0, stream>>>(nfb, Sbf, Mbf, bap, Wb, flagA, outH, Hb, N);
  if (ws_ok)
    k_edge_csr<<<(N+3)/4, 256, 0, stream>>>(Hb, row_ptr, es, outE, N);
  else
    k_edge    <<<(E+7)/8, 256, 0, stream>>>(src, dst, outH, outE, E);
}

// Round 8
// 406.366 us; speedup vs baseline: 1.1365x; 1.0221x over previous
//
#include <hip/hip_runtime.h>

#define D 128

typedef __attribute__((ext_vector_type(4))) float f32x4;
typedef __attribute__((ext_vector_type(8))) short s16x8;

__device__ inline unsigned short f2bf(float x){
  unsigned u = __builtin_bit_cast(unsigned, x);
  u += 0x7FFFu + ((u>>16)&1u);
  return (unsigned short)(u>>16);
}
__device__ inline float bf2f(unsigned short u){
  return __builtin_bit_cast(float, (unsigned)u << 16);
}

__device__ inline void gload_lds16(const void* g, void* l){
  __builtin_amdgcn_global_load_lds(
      (const __attribute__((address_space(1))) void*)g,
      (__attribute__((address_space(3))) void*)l, 16, 0, 0);
}

// ---------- fused preamble: hist + nf->bf16 cvt + comb (independent work) ----------
__global__ void k_pre(const int* __restrict__ dst, int* __restrict__ counts,
                      const float* __restrict__ nf, unsigned short* __restrict__ nfb,
                      const float* __restrict__ Wa, const float* __restrict__ Wm,
                      const float* __restrict__ bm, unsigned short* __restrict__ Mbf,
                      float* __restrict__ Wb,
                      int E, int n8, int nbHist, int nbCvt){
  int b = blockIdx.x, t = threadIdx.x;
  if (b < nbHist){
    int e = b*384 + t;
    if (e < E) atomicAdd(&counts[dst[e]], 1);
  } else if (b < nbHist + nbCvt){
    int i = (b - nbHist)*384 + t;
    if (i < n8){
      const float4* p = reinterpret_cast<const float4*>(nf) + (size_t)i*2;
      float4 a = p[0], bb = p[1];
      union { unsigned short s[8]; uint4 u; } r;
      r.s[0]=f2bf(a.x); r.s[1]=f2bf(a.y); r.s[2]=f2bf(a.z); r.s[3]=f2bf(a.w);
      r.s[4]=f2bf(bb.x); r.s[5]=f2bf(bb.y); r.s[6]=f2bf(bb.z); r.s[7]=f2bf(bb.w);
      reinterpret_cast<uint4*>(nfb)[i] = r.u;
    }
  } else {
    int o = b - nbHist - nbCvt;   // 0..127
    if (t < 128){
      Mbf[o*384+t] = f2bf(Wa[o*256+t]);
    } else {
      int i = t-128;              // 0..255
      float s=0.f;
      #pragma unroll 4
      for (int p=0;p<128;p++) s += Wa[o*256+128+p]*Wm[p*256+i];
      Mbf[o*384+t] = f2bf(s);
    }
    if (t==0){
      float s=0.f;
      for (int p=0;p<128;p++) s += Wa[o*256+128+p]*bm[p];
      Wb[o]=s;
    }
  }
}

// ---------- CSR scans / scatter ----------
__global__ void k_scan1(const int* __restrict__ counts, int* __restrict__ partials, int N){
  __shared__ int sd[256];
  int t = threadIdx.x;
  int base = blockIdx.x*1024 + t*4;
  int s = 0;
  #pragma unroll
  for (int j=0;j<4;j++){ int i=base+j; s += (i<N)?counts[i]:0; }
  sd[t]=s; __syncthreads();
  for (int off=128; off>0; off>>=1){ if (t<off) sd[t]+=sd[t+off]; __syncthreads(); }
  if (t==0) partials[blockIdx.x]=sd[0];
}

__global__ void k_scan2(int* __restrict__ partials, int* __restrict__ row_ptr, int nb, int N){
  __shared__ int sd[1024];
  int t = threadIdx.x;
  if (nb <= 1024){
    int v = (t < nb) ? partials[t] : 0;
    sd[t] = v;
    __syncthreads();
    #pragma unroll
    for (int off=1; off<1024; off<<=1){
      int x = (t >= off) ? sd[t-off] : 0;
      __syncthreads();
      sd[t] += x;
      __syncthreads();
    }
    if (t < nb) partials[t] = sd[t] - v;
    if (t == 1023) row_ptr[N] = sd[1023];
  } else if (t == 0){
    int run=0;
    for (int b=0;b<nb;b++){ int v=partials[b]; partials[b]=run; run+=v; }
    row_ptr[N]=run;
  }
}

__global__ void k_scan3(const int* __restrict__ counts, const int* __restrict__ partials,
                        int* __restrict__ row_ptr, int* __restrict__ cursor, int N){
  __shared__ int sd[256];
  int t=threadIdx.x;
  int base = blockIdx.x*1024 + t*4;
  int v[4]; int s=0;
  #pragma unroll
  for (int j=0;j<4;j++){ int i=base+j; v[j]=(i<N)?counts[i]:0; s+=v[j]; }
  sd[t]=s; __syncthreads();
  for (int off=1; off<256; off<<=1){
    int x = (t>=off)? sd[t-off] : 0;
    __syncthreads();
    sd[t] += x;
    __syncthreads();
  }
  int run = sd[t]-s + partials[blockIdx.x];
  #pragma unroll
  for (int j=0;j<4;j++){ int i=base+j; if (i<N){ row_ptr[i]=run; cursor[i]=run; } run+=v[j]; }
}

__global__ void k_scatter(const int* __restrict__ src, const int* __restrict__ dst,
                          int* __restrict__ cursor, int2* __restrict__ es, int E){
  int e = blockIdx.x*256+threadIdx.x;
  if (e<E){
    int d = dst[e];
    int p = atomicAdd(&cursor[d],1);
    int2 v; v.x = e; v.y = src[e];
    es[p] = v;
  }
}

// ---------- per-node aggregation -> bf16 S + deg flag (unroll-8, deep MLP) ----------
__global__ void k_agg(const unsigned short* __restrict__ nfb, const float* __restrict__ ef,
                      const int* __restrict__ rp, const int2* __restrict__ es,
                      unsigned short* __restrict__ Sbf, float* __restrict__ flagA, int N){
  int n = blockIdx.x*4 + (threadIdx.x>>6);
  int lane = threadIdx.x & 63;
  if (n>=N) return;
  int r0 = rp[n], r1 = rp[n+1];
  float dinv = 1.0f/fmaxf((float)(r1-r0),1.0f);
  float aH0=0.f,aH1=0.f,aE0=0.f,aE1=0.f;
  int j = r0;
  for (; j+8<=r1; j+=8){
    int2 p[8];
    #pragma unroll
    for (int q=0;q<8;q++) p[q] = es[j+q];
    ushort2 h[8]; float2 e2[8];
    #pragma unroll
    for (int q=0;q<8;q++) h[q]  = reinterpret_cast<const ushort2*>(nfb + (size_t)p[q].y*D)[lane];
    #pragma unroll
    for (int q=0;q<8;q++) e2[q] = reinterpret_cast<const float2*>(ef  + (size_t)p[q].x*D)[lane];
    #pragma unroll
    for (int q=0;q<8;q++){
      aH0 += bf2f(h[q].x); aH1 += bf2f(h[q].y);
      aE0 += e2[q].x;      aE1 += e2[q].y;
    }
  }
  for (; j+4<=r1; j+=4){
    int2 p0=es[j], p1=es[j+1], p2=es[j+2], p3=es[j+3];
    ushort2 h0 = reinterpret_cast<const ushort2*>(nfb + (size_t)p0.y*D)[lane];
    ushort2 h1 = reinterpret_cast<const ushort2*>(nfb + (size_t)p1.y*D)[lane];
    ushort2 h2 = reinterpret_cast<const ushort2*>(nfb + (size_t)p2.y*D)[lane];
    ushort2 h3 = reinterpret_cast<const ushort2*>(nfb + (size_t)p3.y*D)[lane];
    float2 e0 = reinterpret_cast<const float2*>(ef + (size_t)p0.x*D)[lane];
    float2 e1 = reinterpret_cast<const float2*>(ef + (size_t)p1.x*D)[lane];
    float2 e2 = reinterpret_cast<const float2*>(ef + (size_t)p2.x*D)[lane];
    float2 e3 = reinterpret_cast<const float2*>(ef + (size_t)p3.x*D)[lane];
    aH0 += (bf2f(h0.x)+bf2f(h1.x))+(bf2f(h2.x)+bf2f(h3.x));
    aH1 += (bf2f(h0.y)+bf2f(h1.y))+(bf2f(h2.y)+bf2f(h3.y));
    aE0 += (e0.x+e1.x)+(e2.x+e3.x);
    aE1 += (e0.y+e1.y)+(e2.y+e3.y);
  }
  for (; j<r1; j++){
    int2 p = es[j];
    ushort2 h = reinterpret_cast<const ushort2*>(nfb + (size_t)p.y*D)[lane];
    float2 e2 = reinterpret_cast<const float2*>(ef + (size_t)p.x*D)[lane];
    aH0+=bf2f(h.x); aH1+=bf2f(h.y); aE0+=e2.x; aE1+=e2.y;
  }
  ushort2* So = reinterpret_cast<ushort2*>(Sbf + (size_t)n*256);
  ushort2 th; th.x = f2bf(aH0*dinv); th.y = f2bf(aH1*dinv);
  ushort2 te; te.x = f2bf(aE0*dinv); te.y = f2bf(aE1*dinv);
  So[lane]    = th;
  So[64+lane] = te;
  if (lane==0) flagA[n] = (r1>r0) ? 1.0f : 0.0f;
}

// ---------- new_h = relu([nf|S]_bf16 * Mbf^T + ba + flag*Wb), MFMA ----------
__global__ __launch_bounds__(256) void k_gemm(
    const unsigned short* __restrict__ nfb, const unsigned short* __restrict__ Sbf,
    const unsigned short* __restrict__ Mbf, const float* __restrict__ ba,
    const float* __restrict__ Wb, const float* __restrict__ flagA,
    float* __restrict__ outH, unsigned short* __restrict__ Hb, int N)
{
  __shared__ __align__(16) unsigned short As[128*32];
  __shared__ __align__(16) unsigned short Bs[128*32];
  int tid = threadIdx.x;
  int lane = tid & 63;
  int w = tid >> 6;
  int wr = w >> 1, wc = w & 1;
  int bn = blockIdx.x * 128;

  f32x4 acc[4][4];
  #pragma unroll
  for (int i=0;i<4;i++)
    #pragma unroll
    for (int j=0;j<4;j++) acc[i][j] = (f32x4){0.f,0.f,0.f,0.f};

  int lr = lane >> 2;
  int lb = (lane & 3) * 16;

  for (int kb = 0; kb < 384; kb += 32){
    #pragma unroll
    for (int c = 0; c < 2; c++){
      int rbase = w*32 + c*16;
      int row = rbase + lr;
      int n = bn + row; if (n >= N) n = N-1;
      const char* g;
      if (kb < 128) g = (const char*)nfb + (size_t)n*256 + (size_t)kb*2 + lb;
      else          g = (const char*)Sbf + (size_t)n*512 + (size_t)(kb-128)*2 + lb;
      gload_lds16(g, &As[rbase*32]);
      const char* gm = (const char*)Mbf + (size_t)row*768 + (size_t)kb*2 + lb;
      gload_lds16(gm, &Bs[rbase*32]);
    }
    __syncthreads();
    s16x8 af[4], bfr[4];
    int kg = (lane>>4)*8;
    #pragma unroll
    for (int bi=0;bi<4;bi++)
      af[bi] = *reinterpret_cast<const s16x8*>(&As[(wr*64 + bi*16 + (lane&15))*32 + kg]);
    #pragma unroll
    for (int bj=0;bj<4;bj++)
      bfr[bj] = *reinterpret_cast<const s16x8*>(&Bs[(wc*64 + bj*16 + (lane&15))*32 + kg]);
    #pragma unroll
    for (int bi=0;bi<4;bi++)
      #pragma unroll
      for (int bj=0;bj<4;bj++)
        acc[bi][bj] = __builtin_amdgcn_mfma_f32_16x16x32_bf16(af[bi], bfr[bj], acc[bi][bj], 0, 0, 0);
    __syncthreads();
  }

  float bav[4], wbv[4];
  #pragma unroll
  for (int bj=0;bj<4;bj++){
    int col = wc*64 + bj*16 + (lane&15);
    bav[bj] = ba[col]; wbv[bj] = Wb[col];
  }
  #pragma unroll
  for (int bi=0;bi<4;bi++){
    int rb = bn + wr*64 + bi*16 + (lane>>4)*4;
    #pragma unroll
    for (int r=0;r<4;r++){
      int row = rb + r;
      if (row < N){
        float fl = flagA[row];
        #pragma unroll
        for (int bj=0;bj<4;bj++){
          int col = wc*64 + bj*16 + (lane&15);
          float v = fmaxf(acc[bi][bj][r] + bav[bj] + fl*wbv[bj], 0.f);
          outH[(size_t)row*128 + col] = v;
          Hb[(size_t)row*128 + col] = f2bf(v);
        }
      }
    }
  }
}

// ---------- new_e in CSR order from bf16 Hb gathers (8 edges in flight/iter) ----------
__global__ void k_edge_csr(const unsigned short* __restrict__ Hb, const int* __restrict__ rp,
                           const int2* __restrict__ es, float* __restrict__ NE, int N){
  int n = blockIdx.x*4 + (threadIdx.x>>6);
  if (n>=N) return;
  int lane = threadIdx.x & 63;
  int half = lane >> 5, l = lane & 31;
  int r0 = rp[n], r1 = rp[n+1];
  const ushort4* H4 = reinterpret_cast<const ushort4*>(Hb);
  float4* NE4 = reinterpret_cast<float4*>(NE);
  ushort4 hnu = H4[(size_t)n*32 + l];
  float4 hn = make_float4(bf2f(hnu.x), bf2f(hnu.y), bf2f(hnu.z), bf2f(hnu.w));
  int j = r0;
  for (; j+8<=r1; j+=8){
    int2 p0 = es[j+half], p1 = es[j+2+half], p2 = es[j+4+half], p3 = es[j+6+half];
    ushort4 u0 = H4[(size_t)p0.y*32 + l];
    ushort4 u1 = H4[(size_t)p1.y*32 + l];
    ushort4 u2 = H4[(size_t)p2.y*32 + l];
    ushort4 u3 = H4[(size_t)p3.y*32 + l];
    float4 o;
    o.x=0.5f*(hn.x+bf2f(u0.x)); o.y=0.5f*(hn.y+bf2f(u0.y));
    o.z=0.5f*(hn.z+bf2f(u0.z)); o.w=0.5f*(hn.w+bf2f(u0.w));
    NE4[(size_t)p0.x*32 + l] = o;
    o.x=0.5f*(hn.x+bf2f(u1.x)); o.y=0.5f*(hn.y+bf2f(u1.y));
    o.z=0.5f*(hn.z+bf2f(u1.z)); o.w=0.5f*(hn.w+bf2f(u1.w));
    NE4[(size_t)p1.x*32 + l] = o;
    o.x=0.5f*(hn.x+bf2f(u2.x)); o.y=0.5f*(hn.y+bf2f(u2.y));
    o.z=0.5f*(hn.z+bf2f(u2.z)); o.w=0.5f*(hn.w+bf2f(u2.w));
    NE4[(size_t)p2.x*32 + l] = o;
    o.x=0.5f*(hn.x+bf2f(u3.x)); o.y=0.5f*(hn.y+bf2f(u3.y));
    o.z=0.5f*(hn.z+bf2f(u3.z)); o.w=0.5f*(hn.w+bf2f(u3.w));
    NE4[(size_t)p3.x*32 + l] = o;
  }
  if (j+4<=r1){
    int2 p0 = es[j+half], p1 = es[j+2+half];
    ushort4 u0 = H4[(size_t)p0.y*32 + l];
    ushort4 u1 = H4[(size_t)p1.y*32 + l];
    float4 o;
    o.x=0.5f*(hn.x+bf2f(u0.x)); o.y=0.5f*(hn.y+bf2f(u0.y));
    o.z=0.5f*(hn.z+bf2f(u0.z)); o.w=0.5f*(hn.w+bf2f(u0.w));
    NE4[(size_t)p0.x*32 + l] = o;
    o.x=0.5f*(hn.x+bf2f(u1.x)); o.y=0.5f*(hn.y+bf2f(u1.y));
    o.z=0.5f*(hn.z+bf2f(u1.z)); o.w=0.5f*(hn.w+bf2f(u1.w));
    NE4[(size_t)p1.x*32 + l] = o;
    j += 4;
  }
  if (j+2<=r1){
    int2 p = es[j+half];
    ushort4 u = H4[(size_t)p.y*32 + l];
    float4 o;
    o.x=0.5f*(hn.x+bf2f(u.x)); o.y=0.5f*(hn.y+bf2f(u.y));
    o.z=0.5f*(hn.z+bf2f(u.z)); o.w=0.5f*(hn.w+bf2f(u.w));
    NE4[(size_t)p.x*32 + l] = o;
    j += 2;
  }
  if (j<r1 && half==0){
    int2 p = es[j];
    ushort4 u = H4[(size_t)p.y*32 + l];
    float4 o;
    o.x=0.5f*(hn.x+bf2f(u.x)); o.y=0.5f*(hn.y+bf2f(u.y));
    o.z=0.5f*(hn.z+bf2f(u.z)); o.w=0.5f*(hn.w+bf2f(u.w));
    NE4[(size_t)p.x*32 + l] = o;
  }
}

// fallback (workspace-in-output mode): edge-order version reading only f32 H
__global__ void k_edge(const int* __restrict__ src, const int* __restrict__ dst,
                       const float* __restrict__ H, float* __restrict__ NE, int E){
  int t = threadIdx.x;
  int e = blockIdx.x*8 + (t>>5);
  if (e>=E) return;
  int l = t & 31;
  const float4* Hs = reinterpret_cast<const float4*>(H + (size_t)src[e]*D);
  const float4* Hd = reinterpret_cast<const float4*>(H + (size_t)dst[e]*D);
  float4 a = Hs[l], b = Hd[l];
  float4 r;
  r.x = 0.5f*(a.x+b.x); r.y = 0.5f*(a.y+b.y);
  r.z = 0.5f*(a.z+b.z); r.w = 0.5f*(a.w+b.w);
  reinterpret_cast<float4*>(NE + (size_t)e*D)[l] = r;
}

extern "C" void kernel_launch(void* const* d_in, const int* in_sizes, int n_in,
                              void* d_out, int out_size, void* d_ws, size_t ws_size,
                              hipStream_t stream)
{
  const float* nf  = (const float*)d_in[0];
  const float* ef  = (const float*)d_in[1];
  const int*   src = (const int*)d_in[2];
  const int*   dst = (const int*)d_in[3];
  const float* Wm  = (const float*)d_in[4];
  const float* bm  = (const float*)d_in[5];
  const float* Wa  = (const float*)d_in[6];
  const float* bap = (const float*)d_in[7];
  int N = in_sizes[0]/D;
  int E = in_sizes[2];
  float* outH = (float*)d_out;
  float* outE = (float*)d_out + (size_t)N*D;

  size_t off = 0;
  auto alloc = [&](size_t bytes){ size_t o = off; off = (off + bytes + 255) & ~(size_t)255; return o; };
  size_t o_counts = alloc((size_t)N*4);
  size_t o_rp     = alloc((size_t)(N+1)*4);
  size_t o_part   = alloc(1024*4);
  size_t o_cur    = alloc((size_t)N*4);
  size_t o_es     = alloc((size_t)E*8);
  size_t o_M      = alloc((size_t)128*384*2);
  size_t o_wb     = alloc(128*4);
  size_t o_S      = alloc((size_t)N*256*2);
  size_t o_nfb    = alloc((size_t)N*128*2);
  size_t o_flag   = alloc((size_t)N*4);
  size_t o_hb     = alloc((size_t)N*128*2);
  size_t need = off;
  bool ws_ok = (ws_size >= need);
  char* base = ws_ok ? (char*)d_ws : (char*)(void*)outE;

  int* counts  = (int*)(base + o_counts);
  int* row_ptr = (int*)(base + o_rp);
  int* partials= (int*)(base + o_part);
  int* cursor  = (int*)(base + o_cur);
  int2* es     = (int2*)(base + o_es);
  unsigned short* Mbf = (unsigned short*)(base + o_M);
  float* Wb    = (float*)(base + o_wb);
  unsigned short* Sbf = (unsigned short*)(base + o_S);
  unsigned short* nfb = (unsigned short*)(base + o_nfb);
  float* flagA = (float*)(base + o_flag);
  unsigned short* Hb  = (unsigned short*)(base + o_hb);

  hipMemsetAsync(counts, 0, (size_t)N*4, stream);

  int n8 = N*16;
  int nbHist = (E + 383)/384;
  int nbCvt  = (n8 + 383)/384;
  int NB = (N + 1023)/1024;
  k_pre    <<<nbHist + nbCvt + 128, 384, 0, stream>>>(dst, counts, nf, nfb, Wa, Wm, bm, Mbf, Wb, E, n8, nbHist, nbCvt);
  k_scan1  <<<NB, 256, 0, stream>>>(counts, partials, N);
  k_scan2  <<<1, 1024, 0, stream>>>(partials, row_ptr, NB, N);
  k_scan3  <<<NB, 256, 0, stream>>>(counts, partials, row_ptr, cursor, N);
  k_scatter<<<(E+255)/256, 256, 0, stream>>>(src, dst, cursor, es, E);
  k_agg    <<<(N+3)/4, 256, 0, stream>>>(nfb, ef, row_ptr, es, Sbf, flagA, N);
  k_gemm   <<<(N+127)/128, 256, 0, stream>>>(nfb, Sbf, Mbf, bap, Wb, flagA, outH, Hb, N);
  if (ws_ok)
    k_edge_csr<<<(N+3)/4, 256, 0, stream>>>(Hb, row_ptr, es, outE, N);
  else
    k_edge    <<<(E+7)/8, 256, 0, stream>>>(src, dst, outH, outE, E);
}

// Round 9
// 399.424 us; speedup vs baseline: 1.1562x; 1.0174x over previous
//
#include <hip/hip_runtime.h>

#define D 128

typedef __attribute__((ext_vector_type(4))) float f32x4;
typedef __attribute__((ext_vector_type(8))) short s16x8;

__device__ inline unsigned short f2bf(float x){
  unsigned u = __builtin_bit_cast(unsigned, x);
  u += 0x7FFFu + ((u>>16)&1u);
  return (unsigned short)(u>>16);
}
__device__ inline float bf2f(unsigned short u){
  return __builtin_bit_cast(float, (unsigned)u << 16);
}

__device__ inline void gload_lds16(const void* g, void* l){
  __builtin_amdgcn_global_load_lds(
      (const __attribute__((address_space(1))) void*)g,
      (__attribute__((address_space(3))) void*)l, 16, 0, 0);
}

// ---------- fused preamble: hist + nf->bf16 cvt + comb (independent work) ----------
__global__ void k_pre(const int* __restrict__ dst, int* __restrict__ counts,
                      const float* __restrict__ nf, unsigned short* __restrict__ nfb,
                      const float* __restrict__ Wa, const float* __restrict__ Wm,
                      const float* __restrict__ bm, unsigned short* __restrict__ Mbf,
                      float* __restrict__ Wb,
                      int E, int n8, int nbHist, int nbCvt){
  int b = blockIdx.x, t = threadIdx.x;
  if (b < nbHist){
    int e = b*384 + t;
    if (e < E) atomicAdd(&counts[dst[e]], 1);
  } else if (b < nbHist + nbCvt){
    int i = (b - nbHist)*384 + t;
    if (i < n8){
      const float4* p = reinterpret_cast<const float4*>(nf) + (size_t)i*2;
      float4 a = p[0], bb = p[1];
      union { unsigned short s[8]; uint4 u; } r;
      r.s[0]=f2bf(a.x); r.s[1]=f2bf(a.y); r.s[2]=f2bf(a.z); r.s[3]=f2bf(a.w);
      r.s[4]=f2bf(bb.x); r.s[5]=f2bf(bb.y); r.s[6]=f2bf(bb.z); r.s[7]=f2bf(bb.w);
      reinterpret_cast<uint4*>(nfb)[i] = r.u;
    }
  } else {
    int o = b - nbHist - nbCvt;   // 0..127
    if (t < 128){
      Mbf[o*384+t] = f2bf(Wa[o*256+t]);
    } else {
      int i = t-128;              // 0..255
      float s=0.f;
      #pragma unroll 4
      for (int p=0;p<128;p++) s += Wa[o*256+128+p]*Wm[p*256+i];
      Mbf[o*384+t] = f2bf(s);
    }
    if (t==0){
      float s=0.f;
      for (int p=0;p<128;p++) s += Wa[o*256+128+p]*bm[p];
      Wb[o]=s;
    }
  }
}

// ---------- CSR scans / scatter ----------
__global__ void k_scan1(const int* __restrict__ counts, int* __restrict__ partials, int N){
  __shared__ int sd[256];
  int t = threadIdx.x;
  int base = blockIdx.x*1024 + t*4;
  int s = 0;
  #pragma unroll
  for (int j=0;j<4;j++){ int i=base+j; s += (i<N)?counts[i]:0; }
  sd[t]=s; __syncthreads();
  for (int off=128; off>0; off>>=1){ if (t<off) sd[t]+=sd[t+off]; __syncthreads(); }
  if (t==0) partials[blockIdx.x]=sd[0];
}

__global__ void k_scan2(int* __restrict__ partials, int* __restrict__ row_ptr, int nb, int N){
  __shared__ int sd[1024];
  int t = threadIdx.x;
  if (nb <= 1024){
    int v = (t < nb) ? partials[t] : 0;
    sd[t] = v;
    __syncthreads();
    #pragma unroll
    for (int off=1; off<1024; off<<=1){
      int x = (t >= off) ? sd[t-off] : 0;
      __syncthreads();
      sd[t] += x;
      __syncthreads();
    }
    if (t < nb) partials[t] = sd[t] - v;
    if (t == 1023) row_ptr[N] = sd[1023];
  } else if (t == 0){
    int run=0;
    for (int b=0;b<nb;b++){ int v=partials[b]; partials[b]=run; run+=v; }
    row_ptr[N]=run;
  }
}

__global__ void k_scan3(const int* __restrict__ counts, const int* __restrict__ partials,
                        int* __restrict__ row_ptr, int* __restrict__ cursor, int N){
  __shared__ int sd[256];
  int t=threadIdx.x;
  int base = blockIdx.x*1024 + t*4;
  int v[4]; int s=0;
  #pragma unroll
  for (int j=0;j<4;j++){ int i=base+j; v[j]=(i<N)?counts[i]:0; s+=v[j]; }
  sd[t]=s; __syncthreads();
  for (int off=1; off<256; off<<=1){
    int x = (t>=off)? sd[t-off] : 0;
    __syncthreads();
    sd[t] += x;
    __syncthreads();
  }
  int run = sd[t]-s + partials[blockIdx.x];
  #pragma unroll
  for (int j=0;j<4;j++){ int i=base+j; if (i<N){ row_ptr[i]=run; cursor[i]=run; } run+=v[j]; }
}

__global__ void k_scatter(const int* __restrict__ src, const int* __restrict__ dst,
                          int* __restrict__ cursor, int2* __restrict__ es, int E){
  int e = blockIdx.x*256+threadIdx.x;
  if (e<E){
    int d = dst[e];
    int p = atomicAdd(&cursor[d],1);
    int2 v; v.x = e; v.y = src[e];
    es[p] = v;
  }
}

// ---------- per-node aggregation: 32 lanes/node, 8 nodes/block ----------
// lane l owns features [4l..4l+3]; ef row = 32 x float4, nfb row = 32 x ushort4.
__global__ void k_agg(const unsigned short* __restrict__ nfb, const float* __restrict__ ef,
                      const int* __restrict__ rp, const int2* __restrict__ es,
                      unsigned short* __restrict__ Sbf, float* __restrict__ flagA, int N){
  int n = blockIdx.x*8 + (threadIdx.x>>5);
  if (n>=N) return;
  int l = threadIdx.x & 31;
  int r0 = rp[n], r1 = rp[n+1];
  float dinv = 1.0f/fmaxf((float)(r1-r0),1.0f);
  const ushort4* nf4 = reinterpret_cast<const ushort4*>(nfb);
  const float4*  ef4 = reinterpret_cast<const float4*>(ef);
  float4 aH = make_float4(0.f,0.f,0.f,0.f), aE = make_float4(0.f,0.f,0.f,0.f);
  int j = r0;
  for (; j+4<=r1; j+=4){
    int2 p[4];
    #pragma unroll
    for (int q=0;q<4;q++) p[q] = es[j+q];
    ushort4 h[4]; float4 e[4];
    #pragma unroll
    for (int q=0;q<4;q++) h[q] = nf4[(size_t)p[q].y*32 + l];
    #pragma unroll
    for (int q=0;q<4;q++) e[q] = ef4[(size_t)p[q].x*32 + l];
    #pragma unroll
    for (int q=0;q<4;q++){
      aH.x += bf2f(h[q].x); aH.y += bf2f(h[q].y); aH.z += bf2f(h[q].z); aH.w += bf2f(h[q].w);
      aE.x += e[q].x; aE.y += e[q].y; aE.z += e[q].z; aE.w += e[q].w;
    }
  }
  for (; j<r1; j++){
    int2 p = es[j];
    ushort4 h = nf4[(size_t)p.y*32 + l];
    float4  e = ef4[(size_t)p.x*32 + l];
    aH.x += bf2f(h.x); aH.y += bf2f(h.y); aH.z += bf2f(h.z); aH.w += bf2f(h.w);
    aE.x += e.x; aE.y += e.y; aE.z += e.z; aE.w += e.w;
  }
  ushort4 oh, oe;
  oh.x=f2bf(aH.x*dinv); oh.y=f2bf(aH.y*dinv); oh.z=f2bf(aH.z*dinv); oh.w=f2bf(aH.w*dinv);
  oe.x=f2bf(aE.x*dinv); oe.y=f2bf(aE.y*dinv); oe.z=f2bf(aE.z*dinv); oe.w=f2bf(aE.w*dinv);
  reinterpret_cast<ushort4*>(Sbf + (size_t)n*256)[l]      = oh;
  reinterpret_cast<ushort4*>(Sbf + (size_t)n*256 + 128)[l]= oe;
  if (l==0) flagA[n] = (r1>r0) ? 1.0f : 0.0f;
}

// ---------- new_h = relu([nf|S]_bf16 * Mbf^T + ba + flag*Wb), MFMA ----------
__global__ __launch_bounds__(256) void k_gemm(
    const unsigned short* __restrict__ nfb, const unsigned short* __restrict__ Sbf,
    const unsigned short* __restrict__ Mbf, const float* __restrict__ ba,
    const float* __restrict__ Wb, const float* __restrict__ flagA,
    float* __restrict__ outH, unsigned short* __restrict__ Hb, int N)
{
  __shared__ __align__(16) unsigned short As[128*32];
  __shared__ __align__(16) unsigned short Bs[128*32];
  int tid = threadIdx.x;
  int lane = tid & 63;
  int w = tid >> 6;
  int wr = w >> 1, wc = w & 1;
  int bn = blockIdx.x * 128;

  f32x4 acc[4][4];
  #pragma unroll
  for (int i=0;i<4;i++)
    #pragma unroll
    for (int j=0;j<4;j++) acc[i][j] = (f32x4){0.f,0.f,0.f,0.f};

  int lr = lane >> 2;
  int lb = (lane & 3) * 16;

  for (int kb = 0; kb < 384; kb += 32){
    #pragma unroll
    for (int c = 0; c < 2; c++){
      int rbase = w*32 + c*16;
      int row = rbase + lr;
      int n = bn + row; if (n >= N) n = N-1;
      const char* g;
      if (kb < 128) g = (const char*)nfb + (size_t)n*256 + (size_t)kb*2 + lb;
      else          g = (const char*)Sbf + (size_t)n*512 + (size_t)(kb-128)*2 + lb;
      gload_lds16(g, &As[rbase*32]);
      const char* gm = (const char*)Mbf + (size_t)row*768 + (size_t)kb*2 + lb;
      gload_lds16(gm, &Bs[rbase*32]);
    }
    __syncthreads();
    s16x8 af[4], bfr[4];
    int kg = (lane>>4)*8;
    #pragma unroll
    for (int bi=0;bi<4;bi++)
      af[bi] = *reinterpret_cast<const s16x8*>(&As[(wr*64 + bi*16 + (lane&15))*32 + kg]);
    #pragma unroll
    for (int bj=0;bj<4;bj++)
      bfr[bj] = *reinterpret_cast<const s16x8*>(&Bs[(wc*64 + bj*16 + (lane&15))*32 + kg]);
    #pragma unroll
    for (int bi=0;bi<4;bi++)
      #pragma unroll
      for (int bj=0;bj<4;bj++)
        acc[bi][bj] = __builtin_amdgcn_mfma_f32_16x16x32_bf16(af[bi], bfr[bj], acc[bi][bj], 0, 0, 0);
    __syncthreads();
  }

  float bav[4], wbv[4];
  #pragma unroll
  for (int bj=0;bj<4;bj++){
    int col = wc*64 + bj*16 + (lane&15);
    bav[bj] = ba[col]; wbv[bj] = Wb[col];
  }
  #pragma unroll
  for (int bi=0;bi<4;bi++){
    int rb = bn + wr*64 + bi*16 + (lane>>4)*4;
    #pragma unroll
    for (int r=0;r<4;r++){
      int row = rb + r;
      if (row < N){
        float fl = flagA[row];
        #pragma unroll
        for (int bj=0;bj<4;bj++){
          int col = wc*64 + bj*16 + (lane&15);
          float v = fmaxf(acc[bi][bj][r] + bav[bj] + fl*wbv[bj], 0.f);
          outH[(size_t)row*128 + col] = v;
          Hb[(size_t)row*128 + col] = f2bf(v);
        }
      }
    }
  }
}

// ---------- new_e in CSR order: 32 lanes/node, 8 nodes/block, unroll-4 ----------
__global__ void k_edge_csr(const unsigned short* __restrict__ Hb, const int* __restrict__ rp,
                           const int2* __restrict__ es, float* __restrict__ NE, int N){
  int n = blockIdx.x*8 + (threadIdx.x>>5);
  if (n>=N) return;
  int l = threadIdx.x & 31;
  int r0 = rp[n], r1 = rp[n+1];
  const ushort4* H4 = reinterpret_cast<const ushort4*>(Hb);
  float4* NE4 = reinterpret_cast<float4*>(NE);
  ushort4 hnu = H4[(size_t)n*32 + l];
  float4 hn = make_float4(bf2f(hnu.x), bf2f(hnu.y), bf2f(hnu.z), bf2f(hnu.w));
  int j = r0;
  for (; j+4<=r1; j+=4){
    int2 p[4];
    #pragma unroll
    for (int q=0;q<4;q++) p[q] = es[j+q];
    ushort4 u[4];
    #pragma unroll
    for (int q=0;q<4;q++) u[q] = H4[(size_t)p[q].y*32 + l];
    #pragma unroll
    for (int q=0;q<4;q++){
      float4 o;
      o.x=0.5f*(hn.x+bf2f(u[q].x)); o.y=0.5f*(hn.y+bf2f(u[q].y));
      o.z=0.5f*(hn.z+bf2f(u[q].z)); o.w=0.5f*(hn.w+bf2f(u[q].w));
      NE4[(size_t)p[q].x*32 + l] = o;
    }
  }
  for (; j<r1; j++){
    int2 p = es[j];
    ushort4 u = H4[(size_t)p.y*32 + l];
    float4 o;
    o.x=0.5f*(hn.x+bf2f(u.x)); o.y=0.5f*(hn.y+bf2f(u.y));
    o.z=0.5f*(hn.z+bf2f(u.z)); o.w=0.5f*(hn.w+bf2f(u.w));
    NE4[(size_t)p.x*32 + l] = o;
  }
}

// fallback (workspace-in-output mode): edge-order version reading only f32 H
__global__ void k_edge(const int* __restrict__ src, const int* __restrict__ dst,
                       const float* __restrict__ H, float* __restrict__ NE, int E){
  int t = threadIdx.x;
  int e = blockIdx.x*8 + (t>>5);
  if (e>=E) return;
  int l = t & 31;
  const float4* Hs = reinterpret_cast<const float4*>(H + (size_t)src[e]*D);
  const float4* Hd = reinterpret_cast<const float4*>(H + (size_t)dst[e]*D);
  float4 a = Hs[l], b = Hd[l];
  float4 r;
  r.x = 0.5f*(a.x+b.x); r.y = 0.5f*(a.y+b.y);
  r.z = 0.5f*(a.z+b.z); r.w = 0.5f*(a.w+b.w);
  reinterpret_cast<float4*>(NE + (size_t)e*D)[l] = r;
}

extern "C" void kernel_launch(void* const* d_in, const int* in_sizes, int n_in,
                              void* d_out, int out_size, void* d_ws, size_t ws_size,
                              hipStream_t stream)
{
  const float* nf  = (const float*)d_in[0];
  const float* ef  = (const float*)d_in[1];
  const int*   src = (const int*)d_in[2];
  const int*   dst = (const int*)d_in[3];
  const float* Wm  = (const float*)d_in[4];
  const float* bm  = (const float*)d_in[5];
  const float* Wa  = (const float*)d_in[6];
  const float* bap = (const float*)d_in[7];
  int N = in_sizes[0]/D;
  int E = in_sizes[2];
  float* outH = (float*)d_out;
  float* outE = (float*)d_out + (size_t)N*D;

  size_t off = 0;
  auto alloc = [&](size_t bytes){ size_t o = off; off = (off + bytes + 255) & ~(size_t)255; return o; };
  size_t o_counts = alloc((size_t)N*4);
  size_t o_rp     = alloc((size_t)(N+1)*4);
  size_t o_part   = alloc(1024*4);
  size_t o_cur    = alloc((size_t)N*4);
  size_t o_es     = alloc((size_t)E*8);
  size_t o_M      = alloc((size_t)128*384*2);
  size_t o_wb     = alloc(128*4);
  size_t o_S      = alloc((size_t)N*256*2);
  size_t o_nfb    = alloc((size_t)N*128*2);
  size_t o_flag   = alloc((size_t)N*4);
  size_t o_hb     = alloc((size_t)N*128*2);
  size_t need = off;
  bool ws_ok = (ws_size >= need);
  char* base = ws_ok ? (char*)d_ws : (char*)(void*)outE;

  int* counts  = (int*)(base + o_counts);
  int* row_ptr = (int*)(base + o_rp);
  int* partials= (int*)(base + o_part);
  int* cursor  = (int*)(base + o_cur);
  int2* es     = (int2*)(base + o_es);
  unsigned short* Mbf = (unsigned short*)(base + o_M);
  float* Wb    = (float*)(base + o_wb);
  unsigned short* Sbf = (unsigned short*)(base + o_S);
  unsigned short* nfb = (unsigned short*)(base + o_nfb);
  float* flagA = (float*)(base + o_flag);
  unsigned short* Hb  = (unsigned short*)(base + o_hb);

  hipMemsetAsync(counts, 0, (size_t)N*4, stream);

  int n8 = N*16;
  int nbHist = (E + 383)/384;
  int nbCvt  = (n8 + 383)/384;
  int NB = (N + 1023)/1024;
  k_pre    <<<nbHist + nbCvt + 128, 384, 0, stream>>>(dst, counts, nf, nfb, Wa, Wm, bm, Mbf, Wb, E, n8, nbHist, nbCvt);
  k_scan1  <<<NB, 256, 0, stream>>>(counts, partials, N);
  k_scan2  <<<1, 1024, 0, stream>>>(partials, row_ptr, NB, N);
  k_scan3  <<<NB, 256, 0, stream>>>(counts, partials, row_ptr, cursor, N);
  k_scatter<<<(E+255)/256, 256, 0, stream>>>(src, dst, cursor, es, E);
  k_agg    <<<(N+7)/8, 256, 0, stream>>>(nfb, ef, row_ptr, es, Sbf, flagA, N);
  k_gemm   <<<(N+127)/128, 256, 0, stream>>>(nfb, Sbf, Mbf, bap, Wb, flagA, outH, Hb, N);
  if (ws_ok)
    k_edge_csr<<<(N+7)/8, 256, 0, stream>>>(Hb, row_ptr, es, outE, N);
  else
    k_edge    <<<(E+7)/8, 256, 0, stream>>>(src, dst, outH, outE, E);
}